// Round 6
// baseline (323.952 us; speedup 1.0000x reference)
//
#include <hip/hip_runtime.h>
#include <hip/hip_bf16.h>
#include <stdint.h>

typedef __attribute__((ext_vector_type(8))) __bf16 bf16x8;
typedef __attribute__((ext_vector_type(4))) __bf16 bf16x4;
typedef __attribute__((ext_vector_type(4))) float f32x4;

#define B_  2
#define H_  16
#define S_  2048
#define D_  128
#define BH_ (B_*H_)

__device__ __forceinline__ uint32_t f2bf1(float f){
  uint32_t u = __builtin_bit_cast(uint32_t, f);
  return (u + 0x7fffu + ((u >> 16) & 1u)) >> 16;
}
__device__ __forceinline__ uint32_t pk2(float a, float b){
  return f2bf1(a) | (f2bf1(b) << 16);
}
__device__ __forceinline__ float bf2f(unsigned short u){
  return __builtin_bit_cast(float, (uint32_t)u << 16);
}

// async global->LDS, 16B/lane, linear LDS dest
__device__ __forceinline__ void gld16(const void* g, void* l){
  __builtin_amdgcn_global_load_lds(
      (const __attribute__((address_space(1))) void*)g,
      (__attribute__((address_space(3))) void*)(uintptr_t)l, 16, 0, 0);
}

// Per-XCD unit table, LPT (heavy-first). code = qb*4 + mode; mode 0=full,
// 1=kv-chunk A (t in [0,qb]), 2=kv-chunk B (t in [qb+1,2qb+1], owns diag).
__device__ const unsigned char TAB_S[24] = {
  61,62,28, 57,58, 24, 53,54, 49,50, 20, 45,46, 41,42, 16, 37,38, 33,34, 12, 8, 4, 0
};

// ---------- zero the control block (replay-safe, no memset-in-capture) ----------
__global__ void zero_ctrl(int* __restrict__ c){
  c[blockIdx.x * 256 + threadIdx.x] = 0;
}

// ---------- fused pre-pass: K->bf16 and V->Vt(bf16, transposed) ----------
__global__ void prep(const float* __restrict__ K, const float* __restrict__ V,
                     unsigned short* __restrict__ Kb, unsigned short* __restrict__ Vt){
  __shared__ __attribute__((aligned(16))) unsigned short t[64*68];
  const int kv0 = blockIdx.x * 64, d0 = blockIdx.y * 64, bh = blockIdx.z;
  const int tid = threadIdx.x;
  const float* Vp = V + (size_t)bh * S_ * D_;
  const float* Kp = K + (size_t)bh * S_ * D_;
  unsigned short* Ko = Kb + (size_t)bh * S_ * D_;
  for (int i = 0; i < 4; i++){
    int f = tid + i*256;
    int kv = f >> 4, c4 = f & 15;
    size_t idx = (size_t)(kv0+kv)*D_ + d0 + c4*4;
    float4 k = *(const float4*)(Kp + idx);
    *(uint2*)(Ko + idx) = make_uint2(pk2(k.x,k.y), pk2(k.z,k.w));
  }
  for (int i = 0; i < 4; i++){
    int f = tid + i*256;
    int kv = f >> 4, c4 = f & 15;
    float4 v = *(const float4*)(Vp + (size_t)(kv0+kv)*D_ + d0 + c4*4);
    *(uint2*)&t[kv*68 + c4*4] = make_uint2(pk2(v.x,v.y), pk2(v.z,v.w));
  }
  __syncthreads();
  unsigned short* Vo = Vt + (size_t)bh * D_ * S_;
  for (int i = 0; i < 4; i++){
    int g = tid + i*256;
    int d = g >> 4, c = g & 15, kv = c*4;
    ushort4 o;
    o.x = t[(kv+0)*68 + d];
    o.y = t[(kv+1)*68 + d];
    o.z = t[(kv+2)*68 + d];
    o.w = t[(kv+3)*68 + d];
    *(ushort4*)(Vo + (size_t)(d0+d)*S_ + kv0 + kv) = o;
  }
}

// ---------- persistent flash-attention kernel (no cross-block waiting) ----------
__global__ __launch_bounds__(256, 2)
void attn_fwd(const float* __restrict__ Q, const unsigned short* __restrict__ Kb,
              const unsigned short* __restrict__ Vt, float* __restrict__ Out,
              unsigned short* __restrict__ Opart, float* __restrict__ MLpart,
              int* __restrict__ ctrl, int splitFlag){
  __shared__ __attribute__((aligned(16))) unsigned short Klds[2][64*128];
  __shared__ __attribute__((aligned(16))) unsigned short Vlds[2][128*64];
  __shared__ __attribute__((aligned(16))) unsigned short Plds[4][2][16*64];
  // broadcast words overlaid on dead Plds bytes (LDS stays at exactly 80 KB)
  int* s_u  = (int*)&Plds[0][0][0];       // byte 0
  int* s_dn = ((int*)&Plds[0][0][0]) + 1; // byte 4

  const int xcd  = blockIdx.x & 7;
  int* cnt  = ctrl + xcd*16;              // 64B-padded per-XCD counters
  int* done = ctrl + 256;                 // 256 per-pair done counters
  const int NU = splitFlag ? 96 : 64;

  const int tid  = threadIdx.x;
  const int wave = tid >> 6, lane = tid & 63;
  const int ql   = lane & 15, hi = lane >> 4;
  const float qs = 0.08838834764831845f * 1.44269504088896f; // scale*log2(e)

  uint32_t koff[4], voff[4];
  #pragma unroll
  for (int i = 0; i < 4; i++){
    int kr = wave*16 + i*4 + (lane >> 4);
    koff[i] = kr*256 + (((lane & 15) ^ ((i & 1)*4 + (lane >> 4))) << 4);
    int vr = wave*32 + i*8 + (lane >> 3);
    voff[i] = vr*(S_*2) + (((lane & 7) ^ (lane >> 3)) << 4);
  }

  for (;;){
    if (tid == 0) *s_u = atomicAdd(cnt, 1);
    __syncthreads();
    const int u = *s_u;
    if (u >= NU) break;

    const int e    = splitFlag ? (int)TAB_S[u >> 2] : ((15 - (u >> 2)) * 4);
    const int bh   = xcd + 8*(u & 3);
    const int qb   = e >> 2, mode = e & 3;
    const int wq0  = qb*128 + wave*32;
    const int t0   = (mode == 2) ? qb + 1 : 0;
    const int tEnd = (mode == 1) ? qb + 1 : 2*qb + 2;
    const int dtw  = (mode == 1) ? (1 << 30) : (2*qb + (wave >> 1));

    const char* Kg = (const char*)(Kb + (size_t)bh * S_ * D_);
    const char* Vg = (const char*)(Vt + (size_t)bh * D_ * S_);

    // Q fragments, pre-scaled (B-operand of swapped QK^T)
    uint4 qf[2][4];
    #pragma unroll
    for (int sub = 0; sub < 2; sub++){
      const float* Qp = Q + ((size_t)bh * S_ + (wq0 + sub*16 + ql)) * D_;
      #pragma unroll
      for (int ks = 0; ks < 4; ks++){
        float4 a = *(const float4*)(Qp + ks*32 + hi*8);
        float4 b = *(const float4*)(Qp + ks*32 + hi*8 + 4);
        bf16x8 q8;
        q8[0] = (__bf16)(a.x*qs); q8[1] = (__bf16)(a.y*qs);
        q8[2] = (__bf16)(a.z*qs); q8[3] = (__bf16)(a.w*qs);
        q8[4] = (__bf16)(b.x*qs); q8[5] = (__bf16)(b.y*qs);
        q8[6] = (__bf16)(b.z*qs); q8[7] = (__bf16)(b.w*qs);
        qf[sub][ks] = __builtin_bit_cast(uint4, q8);
      }
    }

    f32x4 o[2][8];
    #pragma unroll
    for (int sub = 0; sub < 2; sub++)
      #pragma unroll
      for (int nb = 0; nb < 8; nb++) o[sub][nb] = (f32x4)(0.f);
    float m_run[2] = {-INFINITY, -INFINITY};
    float l_run[2] = {0.f, 0.f};

    // prologue stage into buf 0
    {
      const char* kp = Kg + t0*16384;
      const char* vp = Vg + t0*128;
      char* kd = (char*)&Klds[0][0] + wave*4096;
      char* vd = (char*)&Vlds[0][0] + wave*4096;
      #pragma unroll
      for (int i = 0; i < 4; i++){
        gld16(kp + koff[i], kd + i*1024);
        gld16(vp + voff[i], vd + i*1024);
      }
    }
    __syncthreads();

    int cur = 0;
    for (int t = t0; t < tEnd; ++t){
      if (t + 1 < tEnd){
        const char* kp = Kg + (t+1)*16384;
        const char* vp = Vg + (t+1)*128;
        char* kd = (char*)&Klds[cur ^ 1][0] + wave*4096;
        char* vd = (char*)&Vlds[cur ^ 1][0] + wave*4096;
        #pragma unroll
        for (int i = 0; i < 4; i++){
          gld16(kp + koff[i], kd + i*1024);
          gld16(vp + voff[i], vd + i*1024);
        }
      }

      if (t <= dtw){
        const int k0 = t*64;
        const bool diag = (t == dtw);
        const char* Kc = (const char*)&Klds[cur][0];
        const char* Vc = (const char*)&Vlds[cur][0];

        f32x4 sa[2][4];
        __builtin_amdgcn_s_setprio(1);
        #pragma unroll
        for (int mb = 0; mb < 4; mb++){
          sa[0][mb] = (f32x4)(0.f);
          sa[1][mb] = (f32x4)(0.f);
          const int row = ql + mb*16;
          #pragma unroll
          for (int ks = 0; ks < 4; ks++){
            int byte = (row*256 + ks*64 + hi*16) ^ ((row & 7) << 4);
            bf16x8 kf = *(const bf16x8*)(Kc + byte);
            sa[0][mb] = __builtin_amdgcn_mfma_f32_16x16x32_bf16(
                          kf, __builtin_bit_cast(bf16x8, qf[0][ks]), sa[0][mb], 0, 0, 0);
            sa[1][mb] = __builtin_amdgcn_mfma_f32_16x16x32_bf16(
                          kf, __builtin_bit_cast(bf16x8, qf[1][ks]), sa[1][mb], 0, 0, 0);
          }
        }
        __builtin_amdgcn_s_setprio(0);

        #pragma unroll
        for (int sub = 0; sub < 2; sub++){
          float p[16];
          float pm = -INFINITY;
          const int q_abs = wq0 + sub*16 + ql;
          #pragma unroll
          for (int mb = 0; mb < 4; mb++){
            #pragma unroll
            for (int r = 0; r < 4; r++){
              float s = sa[sub][mb][r];
              if (diag){
                int kv = k0 + mb*16 + hi*4 + r;
                if (kv > q_abs) s = -1e30f;
              }
              p[mb*4 + r] = s;
              pm = fmaxf(pm, s);
            }
          }
          pm = fmaxf(pm, __shfl_xor(pm, 16));
          pm = fmaxf(pm, __shfl_xor(pm, 32));
          if (__any(pm > m_run[sub] + 11.5f)){
            float mn  = fmaxf(m_run[sub], pm);
            float fac = exp2f(m_run[sub] - mn);
            float f0 = __shfl(fac, hi*4 + 0), f1 = __shfl(fac, hi*4 + 1);
            float f2 = __shfl(fac, hi*4 + 2), f3 = __shfl(fac, hi*4 + 3);
            #pragma unroll
            for (int nb = 0; nb < 8; nb++){
              o[sub][nb][0] *= f0; o[sub][nb][1] *= f1;
              o[sub][nb][2] *= f2; o[sub][nb][3] *= f3;
            }
            l_run[sub] *= fac;
            m_run[sub] = mn;
          }
          float rs = 0.f;
          #pragma unroll
          for (int q2 = 0; q2 < 16; q2++){ p[q2] = exp2f(p[q2] - m_run[sub]); rs += p[q2]; }
          rs += __shfl_xor(rs, 16);
          rs += __shfl_xor(rs, 32);
          l_run[sub] += rs;

          #pragma unroll
          for (int mb = 0; mb < 4; mb++){
            bf16x4 pv;
            pv[0] = (__bf16)p[mb*4+0]; pv[1] = (__bf16)p[mb*4+1];
            pv[2] = (__bf16)p[mb*4+2]; pv[3] = (__bf16)p[mb*4+3];
            int byte = (ql*128 + mb*32 + hi*8) ^ ((ql & 7) << 4);
            *(bf16x4*)((char*)&Plds[wave][sub][0] + byte) = pv;
          }
        }

        __builtin_amdgcn_s_setprio(1);
        #pragma unroll
        for (int ks = 0; ks < 2; ks++){
          int pb = (ql*128 + ks*64 + hi*16) ^ ((ql & 7) << 4);
          bf16x8 pfA = *(const bf16x8*)((const char*)&Plds[wave][0][0] + pb);
          bf16x8 pfB = *(const bf16x8*)((const char*)&Plds[wave][1][0] + pb);
          #pragma unroll
          for (int nb = 0; nb < 8; nb++){
            int d = ql + nb*16;
            int vb = (d*128 + ks*64 + hi*16) ^ ((d & 7) << 4);
            bf16x8 vf = *(const bf16x8*)(Vc + vb);
            o[0][nb] = __builtin_amdgcn_mfma_f32_16x16x32_bf16(pfA, vf, o[0][nb], 0, 0, 0);
            o[1][nb] = __builtin_amdgcn_mfma_f32_16x16x32_bf16(pfB, vf, o[1][nb], 0, 0, 0);
          }
        }
        __builtin_amdgcn_s_setprio(0);
      }

      __syncthreads();
      cur ^= 1;
    }

    // ---- epilogue
    if (mode == 0){
      #pragma unroll
      for (int sub = 0; sub < 2; sub++){
        float r0 = 1.f / __shfl(l_run[sub], hi*4 + 0);
        float r1 = 1.f / __shfl(l_run[sub], hi*4 + 1);
        float r2 = 1.f / __shfl(l_run[sub], hi*4 + 2);
        float r3 = 1.f / __shfl(l_run[sub], hi*4 + 3);
        float* Op = Out + ((size_t)bh * S_ + wq0 + sub*16) * D_;
        #pragma unroll
        for (int nb = 0; nb < 8; nb++){
          Op[(size_t)(hi*4 + 0)*D_ + nb*16 + ql] = o[sub][nb][0] * r0;
          Op[(size_t)(hi*4 + 1)*D_ + nb*16 + ql] = o[sub][nb][1] * r1;
          Op[(size_t)(hi*4 + 2)*D_ + nb*16 + ql] = o[sub][nb][2] * r2;
          Op[(size_t)(hi*4 + 3)*D_ + nb*16 + ql] = o[sub][nb][3] * r3;
        }
      }
    } else {
      // split pair: write own bf16 partial slot, bump done counter;
      // second arriver merges BOTH slots (deterministic regardless of order).
      const int side = mode - 1;
      const int pair = bh*8 + (qb - 8);
      unsigned short* Po = Opart + (size_t)(pair*2 + side) * (128*128);
      float* Ml = MLpart + (size_t)(pair*2 + side) * 256;
      #pragma unroll
      for (int sub = 0; sub < 2; sub++){
        #pragma unroll
        for (int nb = 0; nb < 8; nb++){
          #pragma unroll
          for (int r = 0; r < 4; r++){
            int row = wave*32 + sub*16 + hi*4 + r;
            __bf16 bv = (__bf16)o[sub][nb][r];
            Po[row*128 + nb*16 + ql] = __builtin_bit_cast(unsigned short, bv);
          }
        }
        if (hi == 0){
          int row = wave*32 + sub*16 + ql;
          Ml[row*2 + 0] = m_run[sub];
          Ml[row*2 + 1] = l_run[sub];
        }
      }
      __threadfence();             // release: write back to coherence point
      __syncthreads();
      if (tid == 0)
        *s_dn = __hip_atomic_fetch_add(&done[pair], 1, __ATOMIC_ACQ_REL,
                                       __HIP_MEMORY_SCOPE_AGENT);
      __syncthreads();
      if (*s_dn == 1){             // I'm second: merge both slots
        __threadfence();           // acquire: invalidate caches
        const unsigned short* P0 = Opart + (size_t)(pair*2) * (128*128);
        const unsigned short* P1 = P0 + 128*128;
        const float* M0 = MLpart + (size_t)(pair*2) * 256;
        const float* M1 = M0 + 256;
        #pragma unroll
        for (int sub = 0; sub < 2; sub++){
          float w0[4], w1[4];
          #pragma unroll
          for (int r = 0; r < 4; r++){
            int row = wave*32 + sub*16 + hi*4 + r;
            float m0 = M0[row*2], l0 = M0[row*2+1];
            float m1 = M1[row*2], l1 = M1[row*2+1];
            float M  = fmaxf(m0, m1);
            float e0 = exp2f(m0 - M), e1 = exp2f(m1 - M);
            float inv = 1.f / (l0*e0 + l1*e1);
            w0[r] = e0*inv; w1[r] = e1*inv;
          }
          float* Op = Out + ((size_t)bh * S_ + wq0 + sub*16) * D_;
          #pragma unroll
          for (int nb = 0; nb < 8; nb++){
            #pragma unroll
            for (int r = 0; r < 4; r++){
              int row = wave*32 + sub*16 + hi*4 + r;
              float a0 = bf2f(P0[row*128 + nb*16 + ql]);
              float a1 = bf2f(P1[row*128 + nb*16 + ql]);
              Op[(size_t)(hi*4 + r)*D_ + nb*16 + ql] = a0*w0[r] + a1*w1[r];
            }
          }
        }
      }
    }
  }
}

extern "C" void kernel_launch(void* const* d_in, const int* in_sizes, int n_in,
                              void* d_out, int out_size, void* d_ws, size_t ws_size,
                              hipStream_t stream){
  const float* Q = (const float*)d_in[0];
  const float* K = (const float*)d_in[1];
  const float* V = (const float*)d_in[2];
  float* Out = (float*)d_out;

  int* ctrl = (int*)d_ws;                                     // 4 KB
  unsigned short* Kb = (unsigned short*)((char*)d_ws + 4096); // 16.78 MB
  unsigned short* Vt = Kb + (size_t)BH_ * S_ * D_;            // 16.78 MB
  unsigned short* Opart = Vt + (size_t)BH_ * S_ * D_;         // 16.78 MB (512 slots x 32KB)
  float* MLpart = (float*)(Opart + (size_t)512 * 128 * 128);  // 0.52 MB

  const size_t need = 4096 + (size_t)BH_*S_*D_*2*2
                    + (size_t)512*128*128*2 + (size_t)512*256*4;
  const int split = (ws_size >= need) ? 1 : 0;

  zero_ctrl<<<4, 256, 0, stream>>>(ctrl);
  prep<<<dim3(S_/64, D_/64, BH_), 256, 0, stream>>>(K, V, Kb, Vt);
  attn_fwd<<<512, 256, 0, stream>>>(Q, Kb, Vt, Out, Opart, MLpart, ctrl, split);
}

// Round 7
// 143.235 us; speedup vs baseline: 2.2617x; 2.2617x over previous
//
#include <hip/hip_runtime.h>
#include <hip/hip_bf16.h>
#include <stdint.h>

typedef __attribute__((ext_vector_type(8))) __bf16 bf16x8;
typedef __attribute__((ext_vector_type(4))) __bf16 bf16x4;
typedef __attribute__((ext_vector_type(4))) float f32x4;

#define B_  2
#define H_  16
#define S_  2048
#define D_  128
#define BH_ (B_*H_)

__device__ __forceinline__ uint32_t f2bf1(float f){
  uint32_t u = __builtin_bit_cast(uint32_t, f);
  return (u + 0x7fffu + ((u >> 16) & 1u)) >> 16;
}
__device__ __forceinline__ uint32_t pk2(float a, float b){
  return f2bf1(a) | (f2bf1(b) << 16);
}
__device__ __forceinline__ float bf2f(unsigned short u){
  return __builtin_bit_cast(float, (uint32_t)u << 16);
}

// async global->LDS, 16B/lane, linear LDS dest
__device__ __forceinline__ void gld16(const void* g, void* l){
  __builtin_amdgcn_global_load_lds(
      (const __attribute__((address_space(1))) void*)g,
      (__attribute__((address_space(3))) void*)(uintptr_t)l, 16, 0, 0);
}

// Per-XCD unit table, LPT (heavy-first). code = qb*4 + mode; mode 0=full,
// 1=kv-chunk A (t in [0,qb]), 2=kv-chunk B (t in [qb+1,2qb+1], owns diag).
__device__ const unsigned char TAB_S[24] = {
  61,62,28, 57,58, 24, 53,54, 49,50, 20, 45,46, 41,42, 16, 37,38, 33,34, 12, 8, 4, 0
};

// ---------- zero the queue counters (replay-safe) ----------
__global__ void zero_ctrl(int* __restrict__ c){ c[threadIdx.x] = 0; }

// ---------- fused pre-pass: K->bf16 and V->Vt(bf16, transposed) ----------
__global__ void prep(const float* __restrict__ K, const float* __restrict__ V,
                     unsigned short* __restrict__ Kb, unsigned short* __restrict__ Vt){
  __shared__ __attribute__((aligned(16))) unsigned short t[64*68];
  const int kv0 = blockIdx.x * 64, d0 = blockIdx.y * 64, bh = blockIdx.z;
  const int tid = threadIdx.x;
  const float* Vp = V + (size_t)bh * S_ * D_;
  const float* Kp = K + (size_t)bh * S_ * D_;
  unsigned short* Ko = Kb + (size_t)bh * S_ * D_;
  for (int i = 0; i < 4; i++){
    int f = tid + i*256;
    int kv = f >> 4, c4 = f & 15;
    size_t idx = (size_t)(kv0+kv)*D_ + d0 + c4*4;
    float4 k = *(const float4*)(Kp + idx);
    *(uint2*)(Ko + idx) = make_uint2(pk2(k.x,k.y), pk2(k.z,k.w));
  }
  for (int i = 0; i < 4; i++){
    int f = tid + i*256;
    int kv = f >> 4, c4 = f & 15;
    float4 v = *(const float4*)(Vp + (size_t)(kv0+kv)*D_ + d0 + c4*4);
    *(uint2*)&t[kv*68 + c4*4] = make_uint2(pk2(v.x,v.y), pk2(v.z,v.w));
  }
  __syncthreads();
  unsigned short* Vo = Vt + (size_t)bh * D_ * S_;
  for (int i = 0; i < 4; i++){
    int g = tid + i*256;
    int d = g >> 4, c = g & 15, kv = c*4;
    ushort4 o;
    o.x = t[(kv+0)*68 + d];
    o.y = t[(kv+1)*68 + d];
    o.z = t[(kv+2)*68 + d];
    o.w = t[(kv+3)*68 + d];
    *(ushort4*)(Vo + (size_t)(d0+d)*S_ + kv0 + kv) = o;
  }
}

// ---------- persistent flash-attention kernel ----------
// Dynamic per-XCD LPT queue (plain relaxed atomicAdd, NO fences, no
// cross-block reads). Split pairs write partials; a separate combine
// kernel (kernel boundary = coherence) merges them.
__global__ __launch_bounds__(256, 2)
void attn_fwd(const float* __restrict__ Q, const unsigned short* __restrict__ Kb,
              const unsigned short* __restrict__ Vt, float* __restrict__ Out,
              unsigned short* __restrict__ Opart, float* __restrict__ MLpart,
              int* __restrict__ ctrl, int splitFlag){
  __shared__ __attribute__((aligned(16))) unsigned short Klds[2][64*128];
  __shared__ __attribute__((aligned(16))) unsigned short Vlds[2][128*64];
  __shared__ __attribute__((aligned(16))) unsigned short Plds[4][2][16*64];
  int* s_u = (int*)&Plds[0][0][0];   // overlaid broadcast word (dead bytes between uses)

  const int xcd = blockIdx.x & 7;
  int* cnt = ctrl + xcd*16;          // 64B-padded per-XCD counters
  const int NU = splitFlag ? 96 : 64;

  const int tid  = threadIdx.x;
  const int wave = tid >> 6, lane = tid & 63;
  const int ql   = lane & 15, hi = lane >> 4;
  const float qs = 0.08838834764831845f * 1.44269504088896f; // scale*log2(e)

  uint32_t koff[4], voff[4];
  #pragma unroll
  for (int i = 0; i < 4; i++){
    int kr = wave*16 + i*4 + (lane >> 4);
    koff[i] = kr*256 + (((lane & 15) ^ ((i & 1)*4 + (lane >> 4))) << 4);
    int vr = wave*32 + i*8 + (lane >> 3);
    voff[i] = vr*(S_*2) + (((lane & 7) ^ (lane >> 3)) << 4);
  }

  for (;;){
    if (tid == 0) *s_u = atomicAdd(cnt, 1);   // relaxed RMW, no fence
    __syncthreads();
    const int u = *s_u;
    if (u >= NU) break;

    const int e    = splitFlag ? (int)TAB_S[u >> 2] : ((15 - (u >> 2)) * 4);
    const int bh   = xcd + 8*(u & 3);
    const int qb   = e >> 2, mode = e & 3;
    const int wq0  = qb*128 + wave*32;
    const int t0   = (mode == 2) ? qb + 1 : 0;
    const int tEnd = (mode == 1) ? qb + 1 : 2*qb + 2;
    const int dtw  = (mode == 1) ? (1 << 30) : (2*qb + (wave >> 1));

    const char* Kg = (const char*)(Kb + (size_t)bh * S_ * D_);
    const char* Vg = (const char*)(Vt + (size_t)bh * D_ * S_);

    // Q fragments, pre-scaled (B-operand of swapped QK^T)
    uint4 qf[2][4];
    #pragma unroll
    for (int sub = 0; sub < 2; sub++){
      const float* Qp = Q + ((size_t)bh * S_ + (wq0 + sub*16 + ql)) * D_;
      #pragma unroll
      for (int ks = 0; ks < 4; ks++){
        float4 a = *(const float4*)(Qp + ks*32 + hi*8);
        float4 b = *(const float4*)(Qp + ks*32 + hi*8 + 4);
        bf16x8 q8;
        q8[0] = (__bf16)(a.x*qs); q8[1] = (__bf16)(a.y*qs);
        q8[2] = (__bf16)(a.z*qs); q8[3] = (__bf16)(a.w*qs);
        q8[4] = (__bf16)(b.x*qs); q8[5] = (__bf16)(b.y*qs);
        q8[6] = (__bf16)(b.z*qs); q8[7] = (__bf16)(b.w*qs);
        qf[sub][ks] = __builtin_bit_cast(uint4, q8);
      }
    }

    f32x4 o[2][8];
    #pragma unroll
    for (int sub = 0; sub < 2; sub++)
      #pragma unroll
      for (int nb = 0; nb < 8; nb++) o[sub][nb] = (f32x4)(0.f);
    float m_run[2] = {-INFINITY, -INFINITY};
    float l_run[2] = {0.f, 0.f};

    // prologue stage into buf 0
    {
      const char* kp = Kg + t0*16384;
      const char* vp = Vg + t0*128;
      char* kd = (char*)&Klds[0][0] + wave*4096;
      char* vd = (char*)&Vlds[0][0] + wave*4096;
      #pragma unroll
      for (int i = 0; i < 4; i++){
        gld16(kp + koff[i], kd + i*1024);
        gld16(vp + voff[i], vd + i*1024);
      }
    }
    __syncthreads();

    int cur = 0;
    for (int t = t0; t < tEnd; ++t){
      if (t + 1 < tEnd){
        const char* kp = Kg + (t+1)*16384;
        const char* vp = Vg + (t+1)*128;
        char* kd = (char*)&Klds[cur ^ 1][0] + wave*4096;
        char* vd = (char*)&Vlds[cur ^ 1][0] + wave*4096;
        #pragma unroll
        for (int i = 0; i < 4; i++){
          gld16(kp + koff[i], kd + i*1024);
          gld16(vp + voff[i], vd + i*1024);
        }
      }

      if (t <= dtw){
        const int k0 = t*64;
        const bool diag = (t == dtw);
        const char* Kc = (const char*)&Klds[cur][0];
        const char* Vc = (const char*)&Vlds[cur][0];

        // ---- swapped QK^T, ks-outer: 8 independent MFMA chains per step
        f32x4 sa[2][4];
        #pragma unroll
        for (int mb = 0; mb < 4; mb++){ sa[0][mb] = (f32x4)(0.f); sa[1][mb] = (f32x4)(0.f); }
        __builtin_amdgcn_s_setprio(1);
        #pragma unroll
        for (int ks = 0; ks < 4; ks++){
          bf16x8 kf[4];
          #pragma unroll
          for (int mb = 0; mb < 4; mb++){
            const int row = ql + mb*16;
            int byte = (row*256 + ks*64 + hi*16) ^ ((row & 7) << 4);
            kf[mb] = *(const bf16x8*)(Kc + byte);
          }
          #pragma unroll
          for (int mb = 0; mb < 4; mb++){
            sa[0][mb] = __builtin_amdgcn_mfma_f32_16x16x32_bf16(
                          kf[mb], __builtin_bit_cast(bf16x8, qf[0][ks]), sa[0][mb], 0, 0, 0);
            sa[1][mb] = __builtin_amdgcn_mfma_f32_16x16x32_bf16(
                          kf[mb], __builtin_bit_cast(bf16x8, qf[1][ks]), sa[1][mb], 0, 0, 0);
          }
        }
        __builtin_amdgcn_s_setprio(0);

        #pragma unroll
        for (int sub = 0; sub < 2; sub++){
          float p[16];
          float pm = -INFINITY;
          const int q_abs = wq0 + sub*16 + ql;
          #pragma unroll
          for (int mb = 0; mb < 4; mb++){
            #pragma unroll
            for (int r = 0; r < 4; r++){
              float s = sa[sub][mb][r];
              if (diag){
                int kv = k0 + mb*16 + hi*4 + r;
                if (kv > q_abs) s = -1e30f;
              }
              p[mb*4 + r] = s;
              pm = fmaxf(pm, s);
            }
          }
          pm = fmaxf(pm, __shfl_xor(pm, 16));
          pm = fmaxf(pm, __shfl_xor(pm, 32));
          if (__any(pm > m_run[sub] + 11.5f)){
            float mn  = fmaxf(m_run[sub], pm);
            float fac = exp2f(m_run[sub] - mn);
            float f0 = __shfl(fac, hi*4 + 0), f1 = __shfl(fac, hi*4 + 1);
            float f2 = __shfl(fac, hi*4 + 2), f3 = __shfl(fac, hi*4 + 3);
            #pragma unroll
            for (int nb = 0; nb < 8; nb++){
              o[sub][nb][0] *= f0; o[sub][nb][1] *= f1;
              o[sub][nb][2] *= f2; o[sub][nb][3] *= f3;
            }
            l_run[sub] *= fac;
            m_run[sub] = mn;
          }
          float rs = 0.f;
          #pragma unroll
          for (int q2 = 0; q2 < 16; q2++){ p[q2] = exp2f(p[q2] - m_run[sub]); rs += p[q2]; }
          rs += __shfl_xor(rs, 16);
          rs += __shfl_xor(rs, 32);
          l_run[sub] += rs;

          #pragma unroll
          for (int mb = 0; mb < 4; mb++){
            bf16x4 pv;
            pv[0] = (__bf16)p[mb*4+0]; pv[1] = (__bf16)p[mb*4+1];
            pv[2] = (__bf16)p[mb*4+2]; pv[3] = (__bf16)p[mb*4+3];
            int byte = (ql*128 + mb*32 + hi*8) ^ ((ql & 7) << 4);
            *(bf16x4*)((char*)&Plds[wave][sub][0] + byte) = pv;
          }
        }

        __builtin_amdgcn_s_setprio(1);
        #pragma unroll
        for (int ks = 0; ks < 2; ks++){
          int pb = (ql*128 + ks*64 + hi*16) ^ ((ql & 7) << 4);
          bf16x8 pfA = *(const bf16x8*)((const char*)&Plds[wave][0][0] + pb);
          bf16x8 pfB = *(const bf16x8*)((const char*)&Plds[wave][1][0] + pb);
          #pragma unroll
          for (int nb = 0; nb < 8; nb++){
            int d = ql + nb*16;
            int vb = (d*128 + ks*64 + hi*16) ^ ((d & 7) << 4);
            bf16x8 vf = *(const bf16x8*)(Vc + vb);
            o[0][nb] = __builtin_amdgcn_mfma_f32_16x16x32_bf16(pfA, vf, o[0][nb], 0, 0, 0);
            o[1][nb] = __builtin_amdgcn_mfma_f32_16x16x32_bf16(pfB, vf, o[1][nb], 0, 0, 0);
          }
        }
        __builtin_amdgcn_s_setprio(0);
      }

      __syncthreads();
      cur ^= 1;
    }

    // ---- epilogue
    if (mode == 0){
      #pragma unroll
      for (int sub = 0; sub < 2; sub++){
        float r0 = 1.f / __shfl(l_run[sub], hi*4 + 0);
        float r1 = 1.f / __shfl(l_run[sub], hi*4 + 1);
        float r2 = 1.f / __shfl(l_run[sub], hi*4 + 2);
        float r3 = 1.f / __shfl(l_run[sub], hi*4 + 3);
        float* Op = Out + ((size_t)bh * S_ + wq0 + sub*16) * D_;
        #pragma unroll
        for (int nb = 0; nb < 8; nb++){
          Op[(size_t)(hi*4 + 0)*D_ + nb*16 + ql] = o[sub][nb][0] * r0;
          Op[(size_t)(hi*4 + 1)*D_ + nb*16 + ql] = o[sub][nb][1] * r1;
          Op[(size_t)(hi*4 + 2)*D_ + nb*16 + ql] = o[sub][nb][2] * r2;
          Op[(size_t)(hi*4 + 3)*D_ + nb*16 + ql] = o[sub][nb][3] * r3;
        }
      }
    } else {
      const int side = mode - 1;
      const int pair = bh*8 + (qb - 8);
      unsigned short* Po = Opart + (size_t)(pair*2 + side) * (128*128);
      float* Ml = MLpart + (size_t)(pair*2 + side) * 256;
      #pragma unroll
      for (int sub = 0; sub < 2; sub++){
        #pragma unroll
        for (int nb = 0; nb < 8; nb++){
          #pragma unroll
          for (int r = 0; r < 4; r++){
            int row = wave*32 + sub*16 + hi*4 + r;
            __bf16 bv = (__bf16)o[sub][nb][r];
            Po[row*128 + nb*16 + ql] = __builtin_bit_cast(unsigned short, bv);
          }
        }
        if (hi == 0){
          int row = wave*32 + sub*16 + ql;
          Ml[row*2 + 0] = m_run[sub];
          Ml[row*2 + 1] = l_run[sub];
        }
      }
    }
  }
}

// ---------- combine kernel: merge the two kv-chunks of qb>=8 ----------
__global__ __launch_bounds__(256)
void combine(const unsigned short* __restrict__ Opart,
             const float* __restrict__ MLpart, float* __restrict__ Out){
  const int blk = blockIdx.x;           // 0..255 = bh*8 + (qb-8)
  const int bh = blk >> 3, qq = blk & 7;
  const unsigned short* A  = Opart + (size_t)(blk*2) * (128*128);
  const unsigned short* Bp = A + 128*128;
  const float* MA = MLpart + (size_t)(blk*2) * 256;
  const float* MB = MA + 256;

  const int row  = threadIdx.x >> 1;
  const int half = threadIdx.x & 1;
  float mA = MA[row*2], lA = MA[row*2 + 1];
  float mB = MB[row*2], lB = MB[row*2 + 1];
  float M  = fmaxf(mA, mB);
  float wA = exp2f(mA - M), wB = exp2f(mB - M);
  float inv = 1.f / (lA*wA + lB*wB);
  wA *= inv; wB *= inv;

  const unsigned short* Ar = A  + row*128 + half*64;
  const unsigned short* Br = Bp + row*128 + half*64;
  float* Or = Out + ((size_t)bh * S_ + (qq + 8)*128 + row) * D_ + half*64;
  #pragma unroll
  for (int c = 0; c < 64; c += 8){
    ushort4 a0 = *(const ushort4*)(Ar + c), a1 = *(const ushort4*)(Ar + c + 4);
    ushort4 b0 = *(const ushort4*)(Br + c), b1 = *(const ushort4*)(Br + c + 4);
    const unsigned short av[8] = {a0.x,a0.y,a0.z,a0.w,a1.x,a1.y,a1.z,a1.w};
    const unsigned short bv[8] = {b0.x,b0.y,b0.z,b0.w,b1.x,b1.y,b1.z,b1.w};
    #pragma unroll
    for (int j = 0; j < 8; j++){
      float fa = bf2f(av[j]);
      float fb = bf2f(bv[j]);
      Or[c + j] = fa*wA + fb*wB;
    }
  }
}

extern "C" void kernel_launch(void* const* d_in, const int* in_sizes, int n_in,
                              void* d_out, int out_size, void* d_ws, size_t ws_size,
                              hipStream_t stream){
  const float* Q = (const float*)d_in[0];
  const float* K = (const float*)d_in[1];
  const float* V = (const float*)d_in[2];
  float* Out = (float*)d_out;

  int* ctrl = (int*)d_ws;                                     // 512 B
  unsigned short* Kb = (unsigned short*)((char*)d_ws + 4096); // 16.78 MB
  unsigned short* Vt = Kb + (size_t)BH_ * S_ * D_;            // 16.78 MB
  unsigned short* Opart = Vt + (size_t)BH_ * S_ * D_;         // 16.78 MB (512 slots x 32KB)
  float* MLpart = (float*)(Opart + (size_t)512 * 128 * 128);  // 0.52 MB

  const size_t need = 4096 + (size_t)BH_*S_*D_*2*2
                    + (size_t)512*128*128*2 + (size_t)512*256*4;
  const int split = (ws_size >= need) ? 1 : 0;

  zero_ctrl<<<1, 128, 0, stream>>>(ctrl);
  prep<<<dim3(S_/64, D_/64, BH_), 256, 0, stream>>>(K, V, Kb, Vt);
  attn_fwd<<<512, 256, 0, stream>>>(Q, Kb, Vt, Out, Opart, MLpart, ctrl, split);
  if (split) combine<<<256, 256, 0, stream>>>(Opart, MLpart, Out);
}